// Round 19
// baseline (112.302 us; speedup 1.0000x reference)
//
#include <hip/hip_runtime.h>

#define N_NODES 100000
#define N_EDGES 1600000
#define IN_FEAT 128
#define OUT_FEAT 64
#define LRELU_SLOPE 0.2f
#define EPS_DENOM 1e-16f

#define SB_SHIFT 7                      // 128 nodes per super-bucket
#define SB_NODES 128
#define NSB 782                         // ceil(100000/128)
#define N_SUB 8                         // XCD-local sub-regions (scatter)
#define SUBA_CAP 384                    // per (SB,sub): mean ~256, +8 sigma
#define STAGE_CAP 2432                  // per-SB LDS stage: mean 2046, +8.5 sigma
#define CH 4096                         // edges per scatter block
#define SCAT_BLOCKS ((N_EDGES + CH - 1) / CH)        // 391
#define GEMM_BLOCKS ((N_NODES + 63) / 64)            // 1563

typedef __attribute__((ext_vector_type(8))) short bf16x8;
typedef __attribute__((ext_vector_type(4))) float f32x4;

// ---- float atomic-max via order-preserving uint encoding ----
__device__ __forceinline__ unsigned int enc_f(float x) {
    unsigned int u = __float_as_uint(x);
    return (u & 0x80000000u) ? ~u : (u | 0x80000000u);
}
__device__ __forceinline__ float dec_f(unsigned int u) {
    u = (u & 0x80000000u) ? (u ^ 0x80000000u) : ~u;
    return __uint_as_float(u);
}
#define ENC_NEG_INF 0x007FFFFFu

__device__ __forceinline__ unsigned short f2bf(float f) {   // RNE
    unsigned int u = __float_as_uint(f);
    u = (u + 0x7FFFu + ((u >> 16) & 1u)) >> 16;
    return (unsigned short)u;
}

// init cursorA + convert W -> bf16 transposed WT[n][k]
__global__ __launch_bounds__(256) void init_prep_kernel(
    const float* __restrict__ W, int* __restrict__ cursorA,
    unsigned short* __restrict__ WTb)
{
    const int i = blockIdx.x * 256 + threadIdx.x;
    if (i < NSB * N_SUB) cursorA[i] = i * SUBA_CAP;      // static sub-region starts
    if (i < OUT_FEAT * IN_FEAT) {
        const int n = i >> 7, k = i & 127;
        WTb[i] = f2bf(W[k * OUT_FEAT + n]);
    }
}

// shared-memory overlays for the heterogeneous fused kernel
struct GemmS {
    unsigned short xs[64][136];   // 17408 B
    float ssp[4][64];
    float stp[4][64];
};
struct ScatS {
    int staged[CH];               // 16384 B, grouped by bucket
    int hcnt[NSB];
    int gbase[NSB];
    int lcnt[NSB];
    int lbase[NSB];
    int pfx[256];
};                                 // ~30 KB

// Heterogeneous fused kernel: blocks [0, SCAT_BLOCKS) = streaming binner with
// LDS-grouped writes; blocks [SCAT_BLOCKS, +GEMM_BLOCKS) = MFMA GEMM.
__global__ __launch_bounds__(256) void gemm_scatter_kernel(
    const float* __restrict__ x, const unsigned short* __restrict__ WTb,
    const float* __restrict__ a, const int* __restrict__ ei,
    int* __restrict__ cursorA, int* __restrict__ bucketsA,
    unsigned short* __restrict__ WhB,
    float* __restrict__ s_src, float* __restrict__ s_tgt)
{
    __shared__ __align__(16) char smem[sizeof(ScatS) > sizeof(GemmS) ? sizeof(ScatS)
                                                                     : sizeof(GemmS)];
    const int tid = threadIdx.x;

    if (blockIdx.x < SCAT_BLOCKS) {
        ScatS& S = *(ScatS*)smem;
        const int base = blockIdx.x * CH;
        const int sub = blockIdx.x & (N_SUB - 1);   // ~XCD id under RR dispatch
        for (int j = tid; j < NSB; j += 256) S.hcnt[j] = 0;
        __syncthreads();
        int tloc[CH / 256], sloc[CH / 256];
        #pragma unroll
        for (int k = 0; k < CH / 256; ++k) {
            const int i = base + k * 256 + tid;
            tloc[k] = (i < N_EDGES) ? ei[N_EDGES + i] : -1;
            sloc[k] = (i < N_EDGES) ? ei[i] : 0;
            if (tloc[k] >= 0) atomicAdd(&S.hcnt[tloc[k] >> SB_SHIFT], 1);
        }
        __syncthreads();
        // exclusive scan hcnt -> lbase via wave-shuffle scan (4 chunks)
        int carry = 0;
        for (int c0 = 0; c0 < NSB; c0 += 256) {
            const int idx = c0 + tid;
            const int v = (idx < NSB) ? S.hcnt[idx] : 0;
            int incl = v;
            #pragma unroll
            for (int off = 1; off < 64; off <<= 1) {
                const int t = __shfl_up(incl, off, 64);
                if ((tid & 63) >= off) incl += t;
            }
            if ((tid & 63) == 63) S.pfx[tid >> 6] = incl;
            __syncthreads();
            int wpre = 0;
            for (int wv = 0; wv < (tid >> 6); ++wv) wpre += S.pfx[wv];
            if (idx < NSB) S.lbase[idx] = carry + wpre + incl - v;
            carry += S.pfx[0] + S.pfx[1] + S.pfx[2] + S.pfx[3];
            __syncthreads();
        }
        for (int j = tid; j < NSB; j += 256) {
            S.lcnt[j] = 0;
            const int c = S.hcnt[j];
            S.gbase[j] = c ? atomicAdd(&cursorA[j * N_SUB + sub], c) : 0;
        }
        __syncthreads();
        #pragma unroll
        for (int k = 0; k < CH / 256; ++k) {
            if (tloc[k] >= 0) {
                const int sb = tloc[k] >> SB_SHIFT;
                const int r = atomicAdd(&S.lcnt[sb], 1);
                S.staged[S.lbase[sb] + r] = sloc[k] | ((tloc[k] & (SB_NODES - 1)) << 17);
            }
        }
        __syncthreads();
        // copy runs out: 8-lane group per bucket (runs ~5 edges now)
        const int grp = tid >> 3, gl = tid & 7;
        for (int sb = grp; sb < NSB; sb += 32) {
            const int c = S.hcnt[sb];
            const int lb = S.lbase[sb];
            const int gb = S.gbase[sb];
            for (int k = gl; k < c; k += 8) bucketsA[gb + k] = S.staged[lb + k];
        }
        return;
    }

    // ---- MFMA GEMM: Wh(bf16) = x @ W, fused score epilogue ----  [frozen]
    GemmS& G = *(GemmS*)smem;
    const int wid = tid >> 6, lane = tid & 63;
    const int r0 = (blockIdx.x - SCAT_BLOCKS) * 64;

    #pragma unroll
    for (int it = 0; it < 8; ++it) {
        const int idx4 = it * 256 + tid;
        const int row = idx4 >> 5;
        const int col = (idx4 & 31) * 4;
        float4 v = make_float4(0.f, 0.f, 0.f, 0.f);
        if (r0 + row < N_NODES) v = *(const float4*)(x + (size_t)(r0 + row) * IN_FEAT + col);
        const unsigned int p0 = (unsigned int)f2bf(v.x) | ((unsigned int)f2bf(v.y) << 16);
        const unsigned int p1 = (unsigned int)f2bf(v.z) | ((unsigned int)f2bf(v.w) << 16);
        *(uint2*)&G.xs[row][col] = make_uint2(p0, p1);
    }
    __syncthreads();

    const int cgrp = lane >> 4;
    const int cl = lane & 15;
    const int col = wid * 16 + cl;
    f32x4 acc0 = {0.f,0.f,0.f,0.f}, acc1 = acc0, acc2 = acc0, acc3 = acc0;
    #pragma unroll
    for (int kb = 0; kb < IN_FEAT; kb += 32) {
        const bf16x8 bfrag = *(const bf16x8*)(WTb + col * IN_FEAT + kb + cgrp * 8);
        const bf16x8 a0 = *(const bf16x8*)&G.xs[ 0 + cl][kb + cgrp * 8];
        const bf16x8 a1 = *(const bf16x8*)&G.xs[16 + cl][kb + cgrp * 8];
        const bf16x8 a2 = *(const bf16x8*)&G.xs[32 + cl][kb + cgrp * 8];
        const bf16x8 a3 = *(const bf16x8*)&G.xs[48 + cl][kb + cgrp * 8];
        acc0 = __builtin_amdgcn_mfma_f32_16x16x32_bf16(a0, bfrag, acc0, 0, 0, 0);
        acc1 = __builtin_amdgcn_mfma_f32_16x16x32_bf16(a1, bfrag, acc1, 0, 0, 0);
        acc2 = __builtin_amdgcn_mfma_f32_16x16x32_bf16(a2, bfrag, acc2, 0, 0, 0);
        acc3 = __builtin_amdgcn_mfma_f32_16x16x32_bf16(a3, bfrag, acc3, 0, 0, 0);
    }

    const float a_s = a[col], a_t = a[OUT_FEAT + col];
    #pragma unroll
    for (int mt = 0; mt < 4; ++mt) {
        const f32x4 av = (mt == 0) ? acc0 : (mt == 1) ? acc1 : (mt == 2) ? acc2 : acc3;
        #pragma unroll
        for (int r = 0; r < 4; ++r) {
            const int lrow = mt * 16 + cgrp * 4 + r;
            const float v = av[r];
            const int grow = r0 + lrow;
            if (grow < N_NODES) WhB[(size_t)grow * OUT_FEAT + col] = f2bf(v);
            float ss = v * a_s;
            float st = v * a_t;
            #pragma unroll
            for (int off = 1; off < 16; off <<= 1) {
                ss += __shfl_xor(ss, off, 64);
                st += __shfl_xor(st, off, 64);
            }
            if (cl == 0) { G.ssp[wid][lrow] = ss; G.stp[wid][lrow] = st; }
        }
    }
    __syncthreads();
    if (tid < 64 && r0 + tid < N_NODES) {
        s_src[r0 + tid] = (G.ssp[0][tid] + G.ssp[1][tid]) + (G.ssp[2][tid] + G.ssp[3][tid]);
        s_tgt[r0 + tid] = (G.stp[0][tid] + G.stp[1][tid]) + (G.stp[2][tid] + G.stp[3][tid]);
    }
}

// Merged sort + aggregation (r17 single-pass structure, 128-node SBs):
// stage+score+count/max -> 2-wave shuffle scan -> deposit (src, w=exp(v-m))
// into LDS sorted -> 16-lane-group aggregation (4 nodes/group) -> ELU -> out.
// LDS ~41.5 KB -> 3 blocks/CU; 782 blocks for fine-grained tail.
__global__ __launch_bounds__(512) void sort_aggr_kernel(
    const int* __restrict__ cursorA, const int* __restrict__ bucketsA,
    const float* __restrict__ s_src, const float* __restrict__ s_tgt,
    const unsigned short* __restrict__ WhB, float* __restrict__ out)
{
    __shared__ int2 stage[STAGE_CAP];          // 19456 B (packed, v)
    __shared__ int2 sorted[STAGE_CAP];         // 19456 B (src, w)
    __shared__ float stgt[SB_NODES];
    __shared__ int cnt[SB_NODES];
    __shared__ int pfx[SB_NODES];              // segment begin
    __shared__ int cur[SB_NODES];
    __shared__ unsigned int m_enc[SB_NODES];
    __shared__ int c_ofs[N_SUB + 1];
    __shared__ int wsum[2];
    const int b = blockIdx.x;
    const int tid = threadIdx.x;

    if (tid < SB_NODES) {
        cnt[tid] = 0;
        m_enc[tid] = ENC_NEG_INF;
        const int node = b * SB_NODES + tid;
        stgt[tid] = (node < N_NODES) ? s_tgt[node] : 0.0f;
    }
    if (tid == 0) {
        int o = 0;
        #pragma unroll
        for (int s = 0; s < N_SUB; ++s) {
            c_ofs[s] = o;
            o += cursorA[b * N_SUB + s] - (b * N_SUB + s) * SUBA_CAP;
        }
        c_ofs[N_SUB] = o;
    }
    __syncthreads();
    const int tot = c_ofs[N_SUB];
    #pragma unroll
    for (int s = 0; s < N_SUB; ++s) {
        const int o = c_ofs[s];
        const int c = c_ofs[s + 1] - o;
        const int* src = bucketsA + (size_t)(b * N_SUB + s) * SUBA_CAP;
        for (int k = tid; k < c; k += 512) {
            const int pk = src[k];
            const int tl = (pk >> 17) & (SB_NODES - 1);
            float v = s_src[pk & 0x1FFFF] + stgt[tl];
            v = (v >= 0.0f) ? v : LRELU_SLOPE * v;
            stage[o + k] = make_int2(pk, __float_as_int(v));
            atomicAdd(&cnt[tl], 1);
            atomicMax(&m_enc[tl], enc_f(v));
        }
    }
    __syncthreads();
    // exclusive scan of 128 counts via 2-wave shuffle scan
    int vv = 0, incl = 0;
    if (tid < SB_NODES) {
        vv = cnt[tid];
        incl = vv;
        #pragma unroll
        for (int off = 1; off < 64; off <<= 1) {
            const int t = __shfl_up(incl, off, 64);
            if ((tid & 63) >= off) incl += t;
        }
        if ((tid & 63) == 63) wsum[tid >> 6] = incl;
    }
    __syncthreads();
    if (tid < SB_NODES) {
        const int wpre = (tid >= 64) ? wsum[0] : 0;
        const int ex = wpre + incl - vv;
        pfx[tid] = ex;
        cur[tid] = ex;
    }
    __syncthreads();
    for (int i = tid; i < tot; i += 512) {
        const int2 pk = stage[i];
        const int tl = (pk.x >> 17) & (SB_NODES - 1);
        const int pos = atomicAdd(&cur[tl], 1);
        const float w = __expf(__int_as_float(pk.y) - dec_f(m_enc[tl]));
        sorted[pos] = make_int2(pk.x & 0x1FFFF, __float_as_int(w));
    }
    __syncthreads();

    // aggregation: 32 groups of 16 lanes; each group handles 4 nodes
    const int grp = tid >> 4, gl = tid & 15;
    const char* whb = (const char*)WhB;
    const unsigned int foff = (unsigned int)gl << 3;   // 8 B (4 bf16 feats)/lane
    #pragma unroll
    for (int n = 0; n < 4; ++n) {
        const int nl = grp * 4 + n;
        const int node = b * SB_NODES + nl;
        if (node >= N_NODES) continue;
        const int beg = pfx[nl];
        const int end = beg + cnt[nl];
        float a0 = 0.f, a1 = 0.f, a2 = 0.f, a3 = 0.f, sum = 0.f;
        int i = beg;
        for (; i + 4 <= end; i += 4) {
            const int2 p0 = sorted[i],     p1 = sorted[i + 1];
            const int2 p2 = sorted[i + 2], p3 = sorted[i + 3];
            const uint2 g0 = *(const uint2*)(whb + (((unsigned int)p0.x << 7) + foff));
            const uint2 g1 = *(const uint2*)(whb + (((unsigned int)p1.x << 7) + foff));
            const uint2 g2 = *(const uint2*)(whb + (((unsigned int)p2.x << 7) + foff));
            const uint2 g3 = *(const uint2*)(whb + (((unsigned int)p3.x << 7) + foff));
            const float w0 = __int_as_float(p0.y), w1 = __int_as_float(p1.y);
            const float w2 = __int_as_float(p2.y), w3 = __int_as_float(p3.y);
            a0 += w0 * __uint_as_float(g0.x << 16) + w1 * __uint_as_float(g1.x << 16)
                + w2 * __uint_as_float(g2.x << 16) + w3 * __uint_as_float(g3.x << 16);
            a1 += w0 * __uint_as_float(g0.x & 0xFFFF0000u) + w1 * __uint_as_float(g1.x & 0xFFFF0000u)
                + w2 * __uint_as_float(g2.x & 0xFFFF0000u) + w3 * __uint_as_float(g3.x & 0xFFFF0000u);
            a2 += w0 * __uint_as_float(g0.y << 16) + w1 * __uint_as_float(g1.y << 16)
                + w2 * __uint_as_float(g2.y << 16) + w3 * __uint_as_float(g3.y << 16);
            a3 += w0 * __uint_as_float(g0.y & 0xFFFF0000u) + w1 * __uint_as_float(g1.y & 0xFFFF0000u)
                + w2 * __uint_as_float(g2.y & 0xFFFF0000u) + w3 * __uint_as_float(g3.y & 0xFFFF0000u);
            sum += (w0 + w1) + (w2 + w3);
        }
        for (; i < end; ++i) {
            const int2 pk = sorted[i];
            const uint2 g0 = *(const uint2*)(whb + (((unsigned int)pk.x << 7) + foff));
            const float w0 = __int_as_float(pk.y);
            a0 += w0 * __uint_as_float(g0.x << 16);
            a1 += w0 * __uint_as_float(g0.x & 0xFFFF0000u);
            a2 += w0 * __uint_as_float(g0.y << 16);
            a3 += w0 * __uint_as_float(g0.y & 0xFFFF0000u);
            sum += w0;
        }
        const float inv = 1.0f / (sum + EPS_DENOM);
        float4 o;
        o.x = a0 * inv; o.y = a1 * inv; o.z = a2 * inv; o.w = a3 * inv;
        o.x = (o.x > 0.f) ? o.x : expm1f(o.x);
        o.y = (o.y > 0.f) ? o.y : expm1f(o.y);
        o.z = (o.z > 0.f) ? o.z : expm1f(o.z);
        o.w = (o.w > 0.f) ? o.w : expm1f(o.w);
        *(float4*)(out + (size_t)node * OUT_FEAT + (gl << 2)) = o;
    }
}

extern "C" void kernel_launch(void* const* d_in, const int* in_sizes, int n_in,
                              void* d_out, int out_size, void* d_ws, size_t ws_size,
                              hipStream_t stream) {
    const float* x  = (const float*)d_in[0];
    const int*   ei = (const int*)d_in[1];     // int64 in reference -> int32 on device
    const float* W  = (const float*)d_in[2];
    const float* a  = (const float*)d_in[3];
    float* out = (float*)d_out;

    // workspace (~24 MB)
    char* p = (char*)d_ws;
    unsigned short* WhB = (unsigned short*)p; p += (size_t)N_NODES * OUT_FEAT * 2; // 12.8 MB
    unsigned short* WTb = (unsigned short*)p; p += (size_t)OUT_FEAT * IN_FEAT * 2; // 16 KB
    float* s_src    = (float*)p;  p += (size_t)N_NODES * 4;
    float* s_tgt    = (float*)p;  p += (size_t)N_NODES * 4;
    int*   cursorA  = (int*)p;    p += (size_t)NSB * N_SUB * 4;
    p = (char*)(((size_t)p + 15) & ~(size_t)15);
    int*   bucketsA = (int*)p;    p += (size_t)NSB * N_SUB * SUBA_CAP * 4;         // 9.6 MB

    init_prep_kernel<<<32, 256, 0, stream>>>(W, cursorA, WTb);
    gemm_scatter_kernel<<<SCAT_BLOCKS + GEMM_BLOCKS, 256, 0, stream>>>(
        x, WTb, a, ei, cursorA, bucketsA, WhB, s_src, s_tgt);
    sort_aggr_kernel<<<NSB, 512, 0, stream>>>(cursorA, bucketsA, s_src, s_tgt, WhB, out);
}

// Round 20
// 94.519 us; speedup vs baseline: 1.1881x; 1.1881x over previous
//
#include <hip/hip_runtime.h>

#define N_NODES 100000
#define N_EDGES 1600000
#define IN_FEAT 128
#define OUT_FEAT 64
#define LRELU_SLOPE 0.2f
#define EPS_DENOM 1e-16f

#define SB_SHIFT 8                      // 256 nodes per super-bucket
#define SB_NODES 256
#define NSB 391                         // ceil(100000/256)
#define N_SUB 8                         // XCD-local sub-regions (scatter)
#define SUBA_CAP 704                    // per (SB,sub): mean ~512, +8.5 sigma
#define STAGE_CAP 4608                  // per-SB sorted LDS: mean 4092, +8 sigma
#define CH 4096                         // edges per scatter block
#define SCAT_BLOCKS ((N_EDGES + CH - 1) / CH)        // 391
#define GEMM_BLOCKS ((N_NODES + 63) / 64)            // 1563

typedef __attribute__((ext_vector_type(8))) short bf16x8;
typedef __attribute__((ext_vector_type(4))) float f32x4;

// ---- float atomic-max via order-preserving uint encoding ----
__device__ __forceinline__ unsigned int enc_f(float x) {
    unsigned int u = __float_as_uint(x);
    return (u & 0x80000000u) ? ~u : (u | 0x80000000u);
}
__device__ __forceinline__ float dec_f(unsigned int u) {
    u = (u & 0x80000000u) ? (u ^ 0x80000000u) : ~u;
    return __uint_as_float(u);
}
#define ENC_NEG_INF 0x007FFFFFu

__device__ __forceinline__ unsigned short f2bf(float f) {   // RNE
    unsigned int u = __float_as_uint(f);
    u = (u + 0x7FFFu + ((u >> 16) & 1u)) >> 16;
    return (unsigned short)u;
}

// init cursorA + convert W -> bf16 transposed WT[n][k]
__global__ __launch_bounds__(256) void init_prep_kernel(
    const float* __restrict__ W, int* __restrict__ cursorA,
    unsigned short* __restrict__ WTb)
{
    const int i = blockIdx.x * 256 + threadIdx.x;
    if (i < NSB * N_SUB) cursorA[i] = i * SUBA_CAP;      // static sub-region starts
    if (i < OUT_FEAT * IN_FEAT) {
        const int n = i >> 7, k = i & 127;
        WTb[i] = f2bf(W[k * OUT_FEAT + n]);
    }
}

// shared-memory overlays for the heterogeneous fused kernel
struct GemmS {
    unsigned short xs[64][136];   // 17408 B
    float ssp[4][64];
    float stp[4][64];
};
struct ScatS {
    int staged[CH];               // 16384 B, grouped by bucket
    int hcnt[NSB];
    int gbase[NSB];
    int lcnt[NSB];
    int lbase[NSB];
    int pfx[256];
};                                 // ~23.7 KB

// Heterogeneous fused kernel: blocks [0, SCAT_BLOCKS) = streaming binner with
// LDS-grouped writes; blocks [SCAT_BLOCKS, +GEMM_BLOCKS) = MFMA GEMM. [r18 body]
__global__ __launch_bounds__(256) void gemm_scatter_kernel(
    const float* __restrict__ x, const unsigned short* __restrict__ WTb,
    const float* __restrict__ a, const int* __restrict__ ei,
    int* __restrict__ cursorA, int* __restrict__ bucketsA,
    unsigned short* __restrict__ WhB,
    float* __restrict__ s_src, float* __restrict__ s_tgt)
{
    __shared__ __align__(16) char smem[sizeof(ScatS) > sizeof(GemmS) ? sizeof(ScatS)
                                                                     : sizeof(GemmS)];
    const int tid = threadIdx.x;

    if (blockIdx.x < SCAT_BLOCKS) {
        ScatS& S = *(ScatS*)smem;
        const int base = blockIdx.x * CH;
        const int sub = blockIdx.x & (N_SUB - 1);   // ~XCD id under RR dispatch
        for (int j = tid; j < NSB; j += 256) S.hcnt[j] = 0;
        __syncthreads();
        int tloc[CH / 256], sloc[CH / 256];
        #pragma unroll
        for (int k = 0; k < CH / 256; ++k) {
            const int i = base + k * 256 + tid;
            tloc[k] = (i < N_EDGES) ? ei[N_EDGES + i] : -1;
            sloc[k] = (i < N_EDGES) ? ei[i] : 0;
            if (tloc[k] >= 0) atomicAdd(&S.hcnt[tloc[k] >> SB_SHIFT], 1);
        }
        __syncthreads();
        // exclusive scan hcnt -> lbase via wave-shuffle scan (2 chunks)
        int carry = 0;
        for (int c0 = 0; c0 < NSB; c0 += 256) {
            const int idx = c0 + tid;
            const int v = (idx < NSB) ? S.hcnt[idx] : 0;
            int incl = v;
            #pragma unroll
            for (int off = 1; off < 64; off <<= 1) {
                const int t = __shfl_up(incl, off, 64);
                if ((tid & 63) >= off) incl += t;
            }
            if ((tid & 63) == 63) S.pfx[tid >> 6] = incl;
            __syncthreads();
            int wpre = 0;
            for (int wv = 0; wv < (tid >> 6); ++wv) wpre += S.pfx[wv];
            if (idx < NSB) S.lbase[idx] = carry + wpre + incl - v;
            carry += S.pfx[0] + S.pfx[1] + S.pfx[2] + S.pfx[3];
            __syncthreads();
        }
        for (int j = tid; j < NSB; j += 256) {
            S.lcnt[j] = 0;
            const int c = S.hcnt[j];
            S.gbase[j] = c ? atomicAdd(&cursorA[j * N_SUB + sub], c) : 0;
        }
        __syncthreads();
        #pragma unroll
        for (int k = 0; k < CH / 256; ++k) {
            if (tloc[k] >= 0) {
                const int sb = tloc[k] >> SB_SHIFT;
                const int r = atomicAdd(&S.lcnt[sb], 1);
                S.staged[S.lbase[sb] + r] = sloc[k] | ((tloc[k] & (SB_NODES - 1)) << 17);
            }
        }
        __syncthreads();
        const int grp = tid >> 4, gl = tid & 15;
        for (int sb = grp; sb < NSB; sb += 16) {
            const int c = S.hcnt[sb];
            const int lb = S.lbase[sb];
            const int gb = S.gbase[sb];
            for (int k = gl; k < c; k += 16) bucketsA[gb + k] = S.staged[lb + k];
        }
        return;
    }

    // ---- MFMA GEMM: Wh(bf16) = x @ W, fused score epilogue ----  [frozen]
    GemmS& G = *(GemmS*)smem;
    const int wid = tid >> 6, lane = tid & 63;
    const int r0 = (blockIdx.x - SCAT_BLOCKS) * 64;

    #pragma unroll
    for (int it = 0; it < 8; ++it) {
        const int idx4 = it * 256 + tid;
        const int row = idx4 >> 5;
        const int col = (idx4 & 31) * 4;
        float4 v = make_float4(0.f, 0.f, 0.f, 0.f);
        if (r0 + row < N_NODES) v = *(const float4*)(x + (size_t)(r0 + row) * IN_FEAT + col);
        const unsigned int p0 = (unsigned int)f2bf(v.x) | ((unsigned int)f2bf(v.y) << 16);
        const unsigned int p1 = (unsigned int)f2bf(v.z) | ((unsigned int)f2bf(v.w) << 16);
        *(uint2*)&G.xs[row][col] = make_uint2(p0, p1);
    }
    __syncthreads();

    const int cgrp = lane >> 4;
    const int cl = lane & 15;
    const int col = wid * 16 + cl;
    f32x4 acc0 = {0.f,0.f,0.f,0.f}, acc1 = acc0, acc2 = acc0, acc3 = acc0;
    #pragma unroll
    for (int kb = 0; kb < IN_FEAT; kb += 32) {
        const bf16x8 bfrag = *(const bf16x8*)(WTb + col * IN_FEAT + kb + cgrp * 8);
        const bf16x8 a0 = *(const bf16x8*)&G.xs[ 0 + cl][kb + cgrp * 8];
        const bf16x8 a1 = *(const bf16x8*)&G.xs[16 + cl][kb + cgrp * 8];
        const bf16x8 a2 = *(const bf16x8*)&G.xs[32 + cl][kb + cgrp * 8];
        const bf16x8 a3 = *(const bf16x8*)&G.xs[48 + cl][kb + cgrp * 8];
        acc0 = __builtin_amdgcn_mfma_f32_16x16x32_bf16(a0, bfrag, acc0, 0, 0, 0);
        acc1 = __builtin_amdgcn_mfma_f32_16x16x32_bf16(a1, bfrag, acc1, 0, 0, 0);
        acc2 = __builtin_amdgcn_mfma_f32_16x16x32_bf16(a2, bfrag, acc2, 0, 0, 0);
        acc3 = __builtin_amdgcn_mfma_f32_16x16x32_bf16(a3, bfrag, acc3, 0, 0, 0);
    }

    const float a_s = a[col], a_t = a[OUT_FEAT + col];
    #pragma unroll
    for (int mt = 0; mt < 4; ++mt) {
        const f32x4 av = (mt == 0) ? acc0 : (mt == 1) ? acc1 : (mt == 2) ? acc2 : acc3;
        #pragma unroll
        for (int r = 0; r < 4; ++r) {
            const int lrow = mt * 16 + cgrp * 4 + r;
            const float v = av[r];
            const int grow = r0 + lrow;
            if (grow < N_NODES) WhB[(size_t)grow * OUT_FEAT + col] = f2bf(v);
            float ss = v * a_s;
            float st = v * a_t;
            #pragma unroll
            for (int off = 1; off < 16; off <<= 1) {
                ss += __shfl_xor(ss, off, 64);
                st += __shfl_xor(st, off, 64);
            }
            if (cl == 0) { G.ssp[wid][lrow] = ss; G.stp[wid][lrow] = st; }
        }
    }
    __syncthreads();
    if (tid < 64 && r0 + tid < N_NODES) {
        s_src[r0 + tid] = (G.ssp[0][tid] + G.ssp[1][tid]) + (G.ssp[2][tid] + G.ssp[3][tid]);
        s_tgt[r0 + tid] = (G.stp[0][tid] + G.stp[1][tid]) + (G.stp[2][tid] + G.stp[3][tid]);
    }
}

// Merged sort + aggregation with REGISTER-staged edges:
// pass 1 reads bucketsA once, holds (pk|rank, v) in statically-indexed regs
// (rank = atomicAdd return), scan, deposit at pfx[tl]+rank (no cur atomics,
// no stage LDS), then 16-lane-group aggregation.  LDS ~41 KB -> 3 blocks/CU.
__global__ __launch_bounds__(512) void sort_aggr_kernel(
    const int* __restrict__ cursorA, const int* __restrict__ bucketsA,
    const float* __restrict__ s_src, const float* __restrict__ s_tgt,
    const unsigned short* __restrict__ WhB, float* __restrict__ out)
{
    __shared__ int2 sorted[STAGE_CAP];         // 36864 B (src, w)
    __shared__ float stgt[SB_NODES];
    __shared__ int cnt[SB_NODES];
    __shared__ int pfx[SB_NODES];              // segment begin
    __shared__ unsigned int m_enc[SB_NODES];
    __shared__ int scnt[N_SUB];
    __shared__ int wsum[4];
    const int b = blockIdx.x;
    const int tid = threadIdx.x;

    if (tid < SB_NODES) {
        cnt[tid] = 0;
        m_enc[tid] = ENC_NEG_INF;
        const int node = b * SB_NODES + tid;
        stgt[tid] = (node < N_NODES) ? s_tgt[node] : 0.0f;
    }
    if (tid < N_SUB) scnt[tid] = cursorA[b * N_SUB + tid] - (b * N_SUB + tid) * SUBA_CAP;
    __syncthreads();

    // pass 1: register staging.  slots = 8 subs x 2 fixed iterations
    // epk[slot] = src[0:17] | tl[17:25] | rank[25:32); validity in bitmask.
    unsigned int epk[16];
    float ev[16];
    int vmask = 0;
    #pragma unroll
    for (int s = 0; s < N_SUB; ++s) {
        const int c = scnt[s];
        const int* srcp = bucketsA + (size_t)(b * N_SUB + s) * SUBA_CAP;
        #pragma unroll
        for (int k2 = 0; k2 < 2; ++k2) {
            const int slot = s * 2 + k2;
            const int k = tid + k2 * 512;
            if (k < c) {
                const int pk = srcp[k];
                const int tl = (pk >> 17) & (SB_NODES - 1);
                float v = s_src[pk & 0x1FFFF] + stgt[tl];
                v = (v >= 0.0f) ? v : LRELU_SLOPE * v;
                const int r = atomicAdd(&cnt[tl], 1);     // rank within node
                atomicMax(&m_enc[tl], enc_f(v));
                epk[slot] = ((unsigned int)pk & 0x1FFFFFFu) | ((unsigned int)r << 25);
                ev[slot] = v;
                vmask |= 1 << slot;
            }
        }
    }
    __syncthreads();

    // exclusive scan of 256 counts via 4-wave shuffle scan
    int vv = 0, incl = 0;
    if (tid < SB_NODES) {
        vv = cnt[tid];
        incl = vv;
        #pragma unroll
        for (int off = 1; off < 64; off <<= 1) {
            const int t = __shfl_up(incl, off, 64);
            if ((tid & 63) >= off) incl += t;
        }
        if ((tid & 63) == 63) wsum[tid >> 6] = incl;
    }
    __syncthreads();
    if (tid < SB_NODES) {
        int wpre = 0;
        for (int wv = 0; wv < (tid >> 6); ++wv) wpre += wsum[wv];
        pfx[tid] = wpre + incl - vv;
    }
    __syncthreads();

    // deposit from registers at pfx[tl] + rank (no atomics)
    #pragma unroll
    for (int slot = 0; slot < 16; ++slot) {
        if (vmask & (1 << slot)) {
            const unsigned int pk = epk[slot];
            const int tl = (int)((pk >> 17) & (SB_NODES - 1));
            const int r = (int)(pk >> 25);
            const float w = __expf(ev[slot] - dec_f(m_enc[tl]));
            sorted[pfx[tl] + r] = make_int2((int)(pk & 0x1FFFFu), __float_as_int(w));
        }
    }
    __syncthreads();

    // aggregation: 32 groups of 16 lanes; each group handles 8 nodes
    const int grp = tid >> 4, gl = tid & 15;
    const char* whb = (const char*)WhB;
    const unsigned int foff = (unsigned int)gl << 3;   // 8 B (4 bf16 feats)/lane
    #pragma unroll
    for (int n = 0; n < 8; ++n) {
        const int nl = grp * 8 + n;
        const int node = b * SB_NODES + nl;
        if (node >= N_NODES) continue;
        const int beg = pfx[nl];
        const int end = beg + cnt[nl];
        float a0 = 0.f, a1 = 0.f, a2 = 0.f, a3 = 0.f, sum = 0.f;
        int i = beg;
        for (; i + 4 <= end; i += 4) {
            const int2 p0 = sorted[i],     p1 = sorted[i + 1];
            const int2 p2 = sorted[i + 2], p3 = sorted[i + 3];
            const uint2 g0 = *(const uint2*)(whb + (((unsigned int)p0.x << 7) + foff));
            const uint2 g1 = *(const uint2*)(whb + (((unsigned int)p1.x << 7) + foff));
            const uint2 g2 = *(const uint2*)(whb + (((unsigned int)p2.x << 7) + foff));
            const uint2 g3 = *(const uint2*)(whb + (((unsigned int)p3.x << 7) + foff));
            const float w0 = __int_as_float(p0.y), w1 = __int_as_float(p1.y);
            const float w2 = __int_as_float(p2.y), w3 = __int_as_float(p3.y);
            a0 += w0 * __uint_as_float(g0.x << 16) + w1 * __uint_as_float(g1.x << 16)
                + w2 * __uint_as_float(g2.x << 16) + w3 * __uint_as_float(g3.x << 16);
            a1 += w0 * __uint_as_float(g0.x & 0xFFFF0000u) + w1 * __uint_as_float(g1.x & 0xFFFF0000u)
                + w2 * __uint_as_float(g2.x & 0xFFFF0000u) + w3 * __uint_as_float(g3.x & 0xFFFF0000u);
            a2 += w0 * __uint_as_float(g0.y << 16) + w1 * __uint_as_float(g1.y << 16)
                + w2 * __uint_as_float(g2.y << 16) + w3 * __uint_as_float(g3.y << 16);
            a3 += w0 * __uint_as_float(g0.y & 0xFFFF0000u) + w1 * __uint_as_float(g1.y & 0xFFFF0000u)
                + w2 * __uint_as_float(g2.y & 0xFFFF0000u) + w3 * __uint_as_float(g3.y & 0xFFFF0000u);
            sum += (w0 + w1) + (w2 + w3);
        }
        for (; i < end; ++i) {
            const int2 pk = sorted[i];
            const uint2 g0 = *(const uint2*)(whb + (((unsigned int)pk.x << 7) + foff));
            const float w0 = __int_as_float(pk.y);
            a0 += w0 * __uint_as_float(g0.x << 16);
            a1 += w0 * __uint_as_float(g0.x & 0xFFFF0000u);
            a2 += w0 * __uint_as_float(g0.y << 16);
            a3 += w0 * __uint_as_float(g0.y & 0xFFFF0000u);
            sum += w0;
        }
        const float inv = 1.0f / (sum + EPS_DENOM);
        float4 o;
        o.x = a0 * inv; o.y = a1 * inv; o.z = a2 * inv; o.w = a3 * inv;
        o.x = (o.x > 0.f) ? o.x : expm1f(o.x);
        o.y = (o.y > 0.f) ? o.y : expm1f(o.y);
        o.z = (o.z > 0.f) ? o.z : expm1f(o.z);
        o.w = (o.w > 0.f) ? o.w : expm1f(o.w);
        *(float4*)(out + (size_t)node * OUT_FEAT + (gl << 2)) = o;
    }
}

extern "C" void kernel_launch(void* const* d_in, const int* in_sizes, int n_in,
                              void* d_out, int out_size, void* d_ws, size_t ws_size,
                              hipStream_t stream) {
    const float* x  = (const float*)d_in[0];
    const int*   ei = (const int*)d_in[1];     // int64 in reference -> int32 on device
    const float* W  = (const float*)d_in[2];
    const float* a  = (const float*)d_in[3];
    float* out = (float*)d_out;

    // workspace (~23 MB)
    char* p = (char*)d_ws;
    unsigned short* WhB = (unsigned short*)p; p += (size_t)N_NODES * OUT_FEAT * 2; // 12.8 MB
    unsigned short* WTb = (unsigned short*)p; p += (size_t)OUT_FEAT * IN_FEAT * 2; // 16 KB
    float* s_src    = (float*)p;  p += (size_t)N_NODES * 4;
    float* s_tgt    = (float*)p;  p += (size_t)N_NODES * 4;
    int*   cursorA  = (int*)p;    p += (size_t)NSB * N_SUB * 4;
    p = (char*)(((size_t)p + 15) & ~(size_t)15);
    int*   bucketsA = (int*)p;    p += (size_t)NSB * N_SUB * SUBA_CAP * 4;         // 8.8 MB

    init_prep_kernel<<<32, 256, 0, stream>>>(W, cursorA, WTb);
    gemm_scatter_kernel<<<SCAT_BLOCKS + GEMM_BLOCKS, 256, 0, stream>>>(
        x, WTb, a, ei, cursorA, bucketsA, WhB, s_src, s_tgt);
    sort_aggr_kernel<<<NSB, 512, 0, stream>>>(cursorA, bucketsA, s_src, s_tgt, WhB, out);
}

// Round 21
// 87.195 us; speedup vs baseline: 1.2879x; 1.0840x over previous
//
#include <hip/hip_runtime.h>

#define N_NODES 100000
#define N_EDGES 1600000
#define IN_FEAT 128
#define OUT_FEAT 64
#define LRELU_SLOPE 0.2f
#define EPS_DENOM 1e-16f

#define SB_SHIFT 8                      // 256 nodes per super-bucket
#define SB_NODES 256
#define NSB 391                         // ceil(100000/256)
#define N_SUB 8                         // XCD-local sub-regions (scatter)
#define SUBA_CAP 704                    // per (SB,sub): mean ~512, +8.5 sigma
#define STAGE_CAP 4608                  // per-SB sorted LDS: mean 4092, +8 sigma
#define CH 4096                         // edges per scatter block
#define SCAT_BLOCKS ((N_EDGES + CH - 1) / CH)        // 391
#define GEMM_BLOCKS ((N_NODES + 63) / 64)            // 1563

typedef __attribute__((ext_vector_type(8))) short bf16x8;
typedef __attribute__((ext_vector_type(4))) float f32x4;

// ---- float atomic-max via order-preserving uint encoding ----
__device__ __forceinline__ unsigned int enc_f(float x) {
    unsigned int u = __float_as_uint(x);
    return (u & 0x80000000u) ? ~u : (u | 0x80000000u);
}
__device__ __forceinline__ float dec_f(unsigned int u) {
    u = (u & 0x80000000u) ? (u ^ 0x80000000u) : ~u;
    return __uint_as_float(u);
}
#define ENC_NEG_INF 0x007FFFFFu

__device__ __forceinline__ unsigned short f2bf(float f) {   // RNE
    unsigned int u = __float_as_uint(f);
    u = (u + 0x7FFFu + ((u >> 16) & 1u)) >> 16;
    return (unsigned short)u;
}

// init cursorA + convert W -> bf16 transposed WT[n][k]
__global__ __launch_bounds__(256) void init_prep_kernel(
    const float* __restrict__ W, int* __restrict__ cursorA,
    unsigned short* __restrict__ WTb)
{
    const int i = blockIdx.x * 256 + threadIdx.x;
    if (i < NSB * N_SUB) cursorA[i] = i * SUBA_CAP;      // static sub-region starts
    if (i < OUT_FEAT * IN_FEAT) {
        const int n = i >> 7, k = i & 127;
        WTb[i] = f2bf(W[k * OUT_FEAT + n]);
    }
}

// shared-memory overlays for the heterogeneous fused kernel
struct GemmS {
    unsigned short xs[64][136];   // 17408 B
    float ssp[4][64];
    float stp[4][64];
};
struct ScatS {
    int staged[CH];               // 16384 B, grouped by bucket
    int hcnt[NSB];
    int gbase[NSB];
    int lcnt[NSB];
    int lbase[NSB];
    int pfx[256];
};                                 // ~23.7 KB

// Heterogeneous fused kernel: blocks [0, SCAT_BLOCKS) = streaming binner with
// LDS-grouped writes; blocks [SCAT_BLOCKS, +GEMM_BLOCKS) = MFMA GEMM. [frozen]
__global__ __launch_bounds__(256) void gemm_scatter_kernel(
    const float* __restrict__ x, const unsigned short* __restrict__ WTb,
    const float* __restrict__ a, const int* __restrict__ ei,
    int* __restrict__ cursorA, int* __restrict__ bucketsA,
    unsigned short* __restrict__ WhB,
    float* __restrict__ s_src, float* __restrict__ s_tgt)
{
    __shared__ __align__(16) char smem[sizeof(ScatS) > sizeof(GemmS) ? sizeof(ScatS)
                                                                     : sizeof(GemmS)];
    const int tid = threadIdx.x;

    if (blockIdx.x < SCAT_BLOCKS) {
        ScatS& S = *(ScatS*)smem;
        const int base = blockIdx.x * CH;
        const int sub = blockIdx.x & (N_SUB - 1);   // ~XCD id under RR dispatch
        for (int j = tid; j < NSB; j += 256) S.hcnt[j] = 0;
        __syncthreads();
        int tloc[CH / 256], sloc[CH / 256];
        #pragma unroll
        for (int k = 0; k < CH / 256; ++k) {
            const int i = base + k * 256 + tid;
            tloc[k] = (i < N_EDGES) ? ei[N_EDGES + i] : -1;
            sloc[k] = (i < N_EDGES) ? ei[i] : 0;
            if (tloc[k] >= 0) atomicAdd(&S.hcnt[tloc[k] >> SB_SHIFT], 1);
        }
        __syncthreads();
        // exclusive scan hcnt -> lbase via wave-shuffle scan (2 chunks)
        int carry = 0;
        for (int c0 = 0; c0 < NSB; c0 += 256) {
            const int idx = c0 + tid;
            const int v = (idx < NSB) ? S.hcnt[idx] : 0;
            int incl = v;
            #pragma unroll
            for (int off = 1; off < 64; off <<= 1) {
                const int t = __shfl_up(incl, off, 64);
                if ((tid & 63) >= off) incl += t;
            }
            if ((tid & 63) == 63) S.pfx[tid >> 6] = incl;
            __syncthreads();
            int wpre = 0;
            for (int wv = 0; wv < (tid >> 6); ++wv) wpre += S.pfx[wv];
            if (idx < NSB) S.lbase[idx] = carry + wpre + incl - v;
            carry += S.pfx[0] + S.pfx[1] + S.pfx[2] + S.pfx[3];
            __syncthreads();
        }
        for (int j = tid; j < NSB; j += 256) {
            S.lcnt[j] = 0;
            const int c = S.hcnt[j];
            S.gbase[j] = c ? atomicAdd(&cursorA[j * N_SUB + sub], c) : 0;
        }
        __syncthreads();
        #pragma unroll
        for (int k = 0; k < CH / 256; ++k) {
            if (tloc[k] >= 0) {
                const int sb = tloc[k] >> SB_SHIFT;
                const int r = atomicAdd(&S.lcnt[sb], 1);
                S.staged[S.lbase[sb] + r] = sloc[k] | ((tloc[k] & (SB_NODES - 1)) << 17);
            }
        }
        __syncthreads();
        const int grp = tid >> 4, gl = tid & 15;
        for (int sb = grp; sb < NSB; sb += 16) {
            const int c = S.hcnt[sb];
            const int lb = S.lbase[sb];
            const int gb = S.gbase[sb];
            for (int k = gl; k < c; k += 16) bucketsA[gb + k] = S.staged[lb + k];
        }
        return;
    }

    // ---- MFMA GEMM: Wh(bf16) = x @ W, fused score epilogue ----  [frozen]
    GemmS& G = *(GemmS*)smem;
    const int wid = tid >> 6, lane = tid & 63;
    const int r0 = (blockIdx.x - SCAT_BLOCKS) * 64;

    #pragma unroll
    for (int it = 0; it < 8; ++it) {
        const int idx4 = it * 256 + tid;
        const int row = idx4 >> 5;
        const int col = (idx4 & 31) * 4;
        float4 v = make_float4(0.f, 0.f, 0.f, 0.f);
        if (r0 + row < N_NODES) v = *(const float4*)(x + (size_t)(r0 + row) * IN_FEAT + col);
        const unsigned int p0 = (unsigned int)f2bf(v.x) | ((unsigned int)f2bf(v.y) << 16);
        const unsigned int p1 = (unsigned int)f2bf(v.z) | ((unsigned int)f2bf(v.w) << 16);
        *(uint2*)&G.xs[row][col] = make_uint2(p0, p1);
    }
    __syncthreads();

    const int cgrp = lane >> 4;
    const int cl = lane & 15;
    const int col = wid * 16 + cl;
    f32x4 acc0 = {0.f,0.f,0.f,0.f}, acc1 = acc0, acc2 = acc0, acc3 = acc0;
    #pragma unroll
    for (int kb = 0; kb < IN_FEAT; kb += 32) {
        const bf16x8 bfrag = *(const bf16x8*)(WTb + col * IN_FEAT + kb + cgrp * 8);
        const bf16x8 a0 = *(const bf16x8*)&G.xs[ 0 + cl][kb + cgrp * 8];
        const bf16x8 a1 = *(const bf16x8*)&G.xs[16 + cl][kb + cgrp * 8];
        const bf16x8 a2 = *(const bf16x8*)&G.xs[32 + cl][kb + cgrp * 8];
        const bf16x8 a3 = *(const bf16x8*)&G.xs[48 + cl][kb + cgrp * 8];
        acc0 = __builtin_amdgcn_mfma_f32_16x16x32_bf16(a0, bfrag, acc0, 0, 0, 0);
        acc1 = __builtin_amdgcn_mfma_f32_16x16x32_bf16(a1, bfrag, acc1, 0, 0, 0);
        acc2 = __builtin_amdgcn_mfma_f32_16x16x32_bf16(a2, bfrag, acc2, 0, 0, 0);
        acc3 = __builtin_amdgcn_mfma_f32_16x16x32_bf16(a3, bfrag, acc3, 0, 0, 0);
    }

    const float a_s = a[col], a_t = a[OUT_FEAT + col];
    #pragma unroll
    for (int mt = 0; mt < 4; ++mt) {
        const f32x4 av = (mt == 0) ? acc0 : (mt == 1) ? acc1 : (mt == 2) ? acc2 : acc3;
        #pragma unroll
        for (int r = 0; r < 4; ++r) {
            const int lrow = mt * 16 + cgrp * 4 + r;
            const float v = av[r];
            const int grow = r0 + lrow;
            if (grow < N_NODES) WhB[(size_t)grow * OUT_FEAT + col] = f2bf(v);
            float ss = v * a_s;
            float st = v * a_t;
            #pragma unroll
            for (int off = 1; off < 16; off <<= 1) {
                ss += __shfl_xor(ss, off, 64);
                st += __shfl_xor(st, off, 64);
            }
            if (cl == 0) { G.ssp[wid][lrow] = ss; G.stp[wid][lrow] = st; }
        }
    }
    __syncthreads();
    if (tid < 64 && r0 + tid < N_NODES) {
        s_src[r0 + tid] = (G.ssp[0][tid] + G.ssp[1][tid]) + (G.ssp[2][tid] + G.ssp[3][tid]);
        s_tgt[r0 + tid] = (G.stp[0][tid] + G.stp[1][tid]) + (G.stp[2][tid] + G.stp[3][tid]);
    }
}

// Merged sort + aggregation, 1024 threads (16 waves/block -> 24 waves/CU avg):
// register-staged edges (8 slots, one per sub), scan, deposit at pfx+rank,
// 64 groups x 16 lanes aggregate 4 nodes each.  LDS ~41 KB -> 2 blocks/CU.
__global__ __launch_bounds__(1024) void sort_aggr_kernel(
    const int* __restrict__ cursorA, const int* __restrict__ bucketsA,
    const float* __restrict__ s_src, const float* __restrict__ s_tgt,
    const unsigned short* __restrict__ WhB, float* __restrict__ out)
{
    __shared__ int2 sorted[STAGE_CAP];         // 36864 B (src, w)
    __shared__ float stgt[SB_NODES];
    __shared__ int cnt[SB_NODES];
    __shared__ int pfx[SB_NODES];              // segment begin
    __shared__ unsigned int m_enc[SB_NODES];
    __shared__ int scnt[N_SUB];
    __shared__ int wsum[4];
    const int b = blockIdx.x;
    const int tid = threadIdx.x;

    if (tid < SB_NODES) {
        cnt[tid] = 0;
        m_enc[tid] = ENC_NEG_INF;
        const int node = b * SB_NODES + tid;
        stgt[tid] = (node < N_NODES) ? s_tgt[node] : 0.0f;
    }
    if (tid < N_SUB) scnt[tid] = cursorA[b * N_SUB + tid] - (b * N_SUB + tid) * SUBA_CAP;
    __syncthreads();

    // pass 1: register staging, 8 slots (1024 threads >= SUBA_CAP)
    // epk[slot] = src[0:17] | tl[17:25] | rank[25:32); validity in bitmask.
    unsigned int epk[N_SUB];
    float ev[N_SUB];
    int vmask = 0;
    #pragma unroll
    for (int s = 0; s < N_SUB; ++s) {
        const int c = scnt[s];
        const int* srcp = bucketsA + (size_t)(b * N_SUB + s) * SUBA_CAP;
        if (tid < c) {
            const int pk = srcp[tid];
            const int tl = (pk >> 17) & (SB_NODES - 1);
            float v = s_src[pk & 0x1FFFF] + stgt[tl];
            v = (v >= 0.0f) ? v : LRELU_SLOPE * v;
            const int r = atomicAdd(&cnt[tl], 1);     // rank within node
            atomicMax(&m_enc[tl], enc_f(v));
            epk[s] = ((unsigned int)pk & 0x1FFFFFFu) | ((unsigned int)r << 25);
            ev[s] = v;
            vmask |= 1 << s;
        }
    }
    __syncthreads();

    // exclusive scan of 256 counts via 4-wave shuffle scan (first 256 threads)
    int vv = 0, incl = 0;
    if (tid < SB_NODES) {
        vv = cnt[tid];
        incl = vv;
        #pragma unroll
        for (int off = 1; off < 64; off <<= 1) {
            const int t = __shfl_up(incl, off, 64);
            if ((tid & 63) >= off) incl += t;
        }
        if ((tid & 63) == 63) wsum[tid >> 6] = incl;
    }
    __syncthreads();
    if (tid < SB_NODES) {
        int wpre = 0;
        for (int wv = 0; wv < (tid >> 6); ++wv) wpre += wsum[wv];
        pfx[tid] = wpre + incl - vv;
    }
    __syncthreads();

    // deposit from registers at pfx[tl] + rank (no atomics)
    #pragma unroll
    for (int s = 0; s < N_SUB; ++s) {
        if (vmask & (1 << s)) {
            const unsigned int pk = epk[s];
            const int tl = (int)((pk >> 17) & (SB_NODES - 1));
            const int r = (int)(pk >> 25);
            const float w = __expf(ev[s] - dec_f(m_enc[tl]));
            sorted[pfx[tl] + r] = make_int2((int)(pk & 0x1FFFFu), __float_as_int(w));
        }
    }
    __syncthreads();

    // aggregation: 64 groups of 16 lanes; each group handles 4 nodes
    const int grp = tid >> 4, gl = tid & 15;
    const char* whb = (const char*)WhB;
    const unsigned int foff = (unsigned int)gl << 3;   // 8 B (4 bf16 feats)/lane
    #pragma unroll
    for (int n = 0; n < 4; ++n) {
        const int nl = grp * 4 + n;
        const int node = b * SB_NODES + nl;
        if (node >= N_NODES) continue;
        const int beg = pfx[nl];
        const int end = beg + cnt[nl];
        float a0 = 0.f, a1 = 0.f, a2 = 0.f, a3 = 0.f, sum = 0.f;
        int i = beg;
        for (; i + 4 <= end; i += 4) {
            const int2 p0 = sorted[i],     p1 = sorted[i + 1];
            const int2 p2 = sorted[i + 2], p3 = sorted[i + 3];
            const uint2 g0 = *(const uint2*)(whb + (((unsigned int)p0.x << 7) + foff));
            const uint2 g1 = *(const uint2*)(whb + (((unsigned int)p1.x << 7) + foff));
            const uint2 g2 = *(const uint2*)(whb + (((unsigned int)p2.x << 7) + foff));
            const uint2 g3 = *(const uint2*)(whb + (((unsigned int)p3.x << 7) + foff));
            const float w0 = __int_as_float(p0.y), w1 = __int_as_float(p1.y);
            const float w2 = __int_as_float(p2.y), w3 = __int_as_float(p3.y);
            a0 += w0 * __uint_as_float(g0.x << 16) + w1 * __uint_as_float(g1.x << 16)
                + w2 * __uint_as_float(g2.x << 16) + w3 * __uint_as_float(g3.x << 16);
            a1 += w0 * __uint_as_float(g0.x & 0xFFFF0000u) + w1 * __uint_as_float(g1.x & 0xFFFF0000u)
                + w2 * __uint_as_float(g2.x & 0xFFFF0000u) + w3 * __uint_as_float(g3.x & 0xFFFF0000u);
            a2 += w0 * __uint_as_float(g0.y << 16) + w1 * __uint_as_float(g1.y << 16)
                + w2 * __uint_as_float(g2.y << 16) + w3 * __uint_as_float(g3.y << 16);
            a3 += w0 * __uint_as_float(g0.y & 0xFFFF0000u) + w1 * __uint_as_float(g1.y & 0xFFFF0000u)
                + w2 * __uint_as_float(g2.y & 0xFFFF0000u) + w3 * __uint_as_float(g3.y & 0xFFFF0000u);
            sum += (w0 + w1) + (w2 + w3);
        }
        for (; i < end; ++i) {
            const int2 pk = sorted[i];
            const uint2 g0 = *(const uint2*)(whb + (((unsigned int)pk.x << 7) + foff));
            const float w0 = __int_as_float(pk.y);
            a0 += w0 * __uint_as_float(g0.x << 16);
            a1 += w0 * __uint_as_float(g0.x & 0xFFFF0000u);
            a2 += w0 * __uint_as_float(g0.y << 16);
            a3 += w0 * __uint_as_float(g0.y & 0xFFFF0000u);
            sum += w0;
        }
        const float inv = 1.0f / (sum + EPS_DENOM);
        float4 o;
        o.x = a0 * inv; o.y = a1 * inv; o.z = a2 * inv; o.w = a3 * inv;
        o.x = (o.x > 0.f) ? o.x : expm1f(o.x);
        o.y = (o.y > 0.f) ? o.y : expm1f(o.y);
        o.z = (o.z > 0.f) ? o.z : expm1f(o.z);
        o.w = (o.w > 0.f) ? o.w : expm1f(o.w);
        *(float4*)(out + (size_t)node * OUT_FEAT + (gl << 2)) = o;
    }
}

extern "C" void kernel_launch(void* const* d_in, const int* in_sizes, int n_in,
                              void* d_out, int out_size, void* d_ws, size_t ws_size,
                              hipStream_t stream) {
    const float* x  = (const float*)d_in[0];
    const int*   ei = (const int*)d_in[1];     // int64 in reference -> int32 on device
    const float* W  = (const float*)d_in[2];
    const float* a  = (const float*)d_in[3];
    float* out = (float*)d_out;

    // workspace (~23 MB)
    char* p = (char*)d_ws;
    unsigned short* WhB = (unsigned short*)p; p += (size_t)N_NODES * OUT_FEAT * 2; // 12.8 MB
    unsigned short* WTb = (unsigned short*)p; p += (size_t)OUT_FEAT * IN_FEAT * 2; // 16 KB
    float* s_src    = (float*)p;  p += (size_t)N_NODES * 4;
    float* s_tgt    = (float*)p;  p += (size_t)N_NODES * 4;
    int*   cursorA  = (int*)p;    p += (size_t)NSB * N_SUB * 4;
    p = (char*)(((size_t)p + 15) & ~(size_t)15);
    int*   bucketsA = (int*)p;    p += (size_t)NSB * N_SUB * SUBA_CAP * 4;         // 8.8 MB

    init_prep_kernel<<<32, 256, 0, stream>>>(W, cursorA, WTb);
    gemm_scatter_kernel<<<SCAT_BLOCKS + GEMM_BLOCKS, 256, 0, stream>>>(
        x, WTb, a, ei, cursorA, bucketsA, WhB, s_src, s_tgt);
    sort_aggr_kernel<<<NSB, 1024, 0, stream>>>(cursorA, bucketsA, s_src, s_tgt, WhB, out);
}

// Round 22
// 86.480 us; speedup vs baseline: 1.2986x; 1.0083x over previous
//
#include <hip/hip_runtime.h>

#define N_NODES 100000
#define N_EDGES 1600000
#define IN_FEAT 128
#define OUT_FEAT 64
#define LRELU_SLOPE 0.2f
#define EPS_DENOM 1e-16f

#define SB_SHIFT 8                      // 256 nodes per super-bucket
#define SB_NODES 256
#define NSB 391                         // ceil(100000/256)
#define N_SUB 8                         // XCD-local sub-regions (scatter)
#define SUBA_CAP 704                    // per (SB,sub): mean ~512, +8.5 sigma
#define STAGE_CAP 4608                  // per-SB sorted LDS: mean 4092, +8 sigma
#define CH 4096                         // edges per scatter block
#define SCAT_BLOCKS ((N_EDGES + CH - 1) / CH)        // 391
#define GEMM_BLOCKS ((N_NODES + 63) / 64)            // 1563

typedef __attribute__((ext_vector_type(8))) short bf16x8;
typedef __attribute__((ext_vector_type(4))) float f32x4;

// ---- float atomic-max via order-preserving uint encoding ----
__device__ __forceinline__ unsigned int enc_f(float x) {
    unsigned int u = __float_as_uint(x);
    return (u & 0x80000000u) ? ~u : (u | 0x80000000u);
}
__device__ __forceinline__ float dec_f(unsigned int u) {
    u = (u & 0x80000000u) ? (u ^ 0x80000000u) : ~u;
    return __uint_as_float(u);
}
#define ENC_NEG_INF 0x007FFFFFu

__device__ __forceinline__ unsigned short f2bf(float f) {   // RNE
    unsigned int u = __float_as_uint(f);
    u = (u + 0x7FFFu + ((u >> 16) & 1u)) >> 16;
    return (unsigned short)u;
}

// init cursorA + convert W -> bf16 transposed WT[n][k]
__global__ __launch_bounds__(256) void init_prep_kernel(
    const float* __restrict__ W, int* __restrict__ cursorA,
    unsigned short* __restrict__ WTb)
{
    const int i = blockIdx.x * 256 + threadIdx.x;
    if (i < NSB * N_SUB) cursorA[i] = i * SUBA_CAP;      // static sub-region starts
    if (i < OUT_FEAT * IN_FEAT) {
        const int n = i >> 7, k = i & 127;
        WTb[i] = f2bf(W[k * OUT_FEAT + n]);
    }
}

// shared-memory overlays for the heterogeneous fused kernel
struct GemmS {
    unsigned short xs[64][136];   // 17408 B
    float ssp[4][64];
    float stp[4][64];
};
struct ScatS {
    int staged[CH];               // 16384 B, grouped by bucket
    int hcnt[NSB];
    int gbase[NSB];
    int lcnt[NSB];
    int lbase[NSB];
    int pfx[256];
};                                 // ~23.7 KB

// Heterogeneous fused kernel: blocks [0, SCAT_BLOCKS) = streaming binner with
// LDS-grouped writes; blocks [SCAT_BLOCKS, +GEMM_BLOCKS) = MFMA GEMM. [frozen]
__global__ __launch_bounds__(256) void gemm_scatter_kernel(
    const float* __restrict__ x, const unsigned short* __restrict__ WTb,
    const float* __restrict__ a, const int* __restrict__ ei,
    int* __restrict__ cursorA, int* __restrict__ bucketsA,
    unsigned short* __restrict__ WhB,
    float* __restrict__ s_src, float* __restrict__ s_tgt)
{
    __shared__ __align__(16) char smem[sizeof(ScatS) > sizeof(GemmS) ? sizeof(ScatS)
                                                                     : sizeof(GemmS)];
    const int tid = threadIdx.x;

    if (blockIdx.x < SCAT_BLOCKS) {
        ScatS& S = *(ScatS*)smem;
        const int base = blockIdx.x * CH;
        const int sub = blockIdx.x & (N_SUB - 1);   // ~XCD id under RR dispatch
        for (int j = tid; j < NSB; j += 256) S.hcnt[j] = 0;
        __syncthreads();
        int tloc[CH / 256], sloc[CH / 256];
        #pragma unroll
        for (int k = 0; k < CH / 256; ++k) {
            const int i = base + k * 256 + tid;
            tloc[k] = (i < N_EDGES) ? ei[N_EDGES + i] : -1;
            sloc[k] = (i < N_EDGES) ? ei[i] : 0;
            if (tloc[k] >= 0) atomicAdd(&S.hcnt[tloc[k] >> SB_SHIFT], 1);
        }
        __syncthreads();
        // exclusive scan hcnt -> lbase via wave-shuffle scan (2 chunks)
        int carry = 0;
        for (int c0 = 0; c0 < NSB; c0 += 256) {
            const int idx = c0 + tid;
            const int v = (idx < NSB) ? S.hcnt[idx] : 0;
            int incl = v;
            #pragma unroll
            for (int off = 1; off < 64; off <<= 1) {
                const int t = __shfl_up(incl, off, 64);
                if ((tid & 63) >= off) incl += t;
            }
            if ((tid & 63) == 63) S.pfx[tid >> 6] = incl;
            __syncthreads();
            int wpre = 0;
            for (int wv = 0; wv < (tid >> 6); ++wv) wpre += S.pfx[wv];
            if (idx < NSB) S.lbase[idx] = carry + wpre + incl - v;
            carry += S.pfx[0] + S.pfx[1] + S.pfx[2] + S.pfx[3];
            __syncthreads();
        }
        for (int j = tid; j < NSB; j += 256) {
            S.lcnt[j] = 0;
            const int c = S.hcnt[j];
            S.gbase[j] = c ? atomicAdd(&cursorA[j * N_SUB + sub], c) : 0;
        }
        __syncthreads();
        #pragma unroll
        for (int k = 0; k < CH / 256; ++k) {
            if (tloc[k] >= 0) {
                const int sb = tloc[k] >> SB_SHIFT;
                const int r = atomicAdd(&S.lcnt[sb], 1);
                S.staged[S.lbase[sb] + r] = sloc[k] | ((tloc[k] & (SB_NODES - 1)) << 17);
            }
        }
        __syncthreads();
        const int grp = tid >> 4, gl = tid & 15;
        for (int sb = grp; sb < NSB; sb += 16) {
            const int c = S.hcnt[sb];
            const int lb = S.lbase[sb];
            const int gb = S.gbase[sb];
            for (int k = gl; k < c; k += 16) bucketsA[gb + k] = S.staged[lb + k];
        }
        return;
    }

    // ---- MFMA GEMM: Wh(bf16) = x @ W, fused score epilogue ----  [frozen]
    GemmS& G = *(GemmS*)smem;
    const int wid = tid >> 6, lane = tid & 63;
    const int r0 = (blockIdx.x - SCAT_BLOCKS) * 64;

    #pragma unroll
    for (int it = 0; it < 8; ++it) {
        const int idx4 = it * 256 + tid;
        const int row = idx4 >> 5;
        const int col = (idx4 & 31) * 4;
        float4 v = make_float4(0.f, 0.f, 0.f, 0.f);
        if (r0 + row < N_NODES) v = *(const float4*)(x + (size_t)(r0 + row) * IN_FEAT + col);
        const unsigned int p0 = (unsigned int)f2bf(v.x) | ((unsigned int)f2bf(v.y) << 16);
        const unsigned int p1 = (unsigned int)f2bf(v.z) | ((unsigned int)f2bf(v.w) << 16);
        *(uint2*)&G.xs[row][col] = make_uint2(p0, p1);
    }
    __syncthreads();

    const int cgrp = lane >> 4;
    const int cl = lane & 15;
    const int col = wid * 16 + cl;
    f32x4 acc0 = {0.f,0.f,0.f,0.f}, acc1 = acc0, acc2 = acc0, acc3 = acc0;
    #pragma unroll
    for (int kb = 0; kb < IN_FEAT; kb += 32) {
        const bf16x8 bfrag = *(const bf16x8*)(WTb + col * IN_FEAT + kb + cgrp * 8);
        const bf16x8 a0 = *(const bf16x8*)&G.xs[ 0 + cl][kb + cgrp * 8];
        const bf16x8 a1 = *(const bf16x8*)&G.xs[16 + cl][kb + cgrp * 8];
        const bf16x8 a2 = *(const bf16x8*)&G.xs[32 + cl][kb + cgrp * 8];
        const bf16x8 a3 = *(const bf16x8*)&G.xs[48 + cl][kb + cgrp * 8];
        acc0 = __builtin_amdgcn_mfma_f32_16x16x32_bf16(a0, bfrag, acc0, 0, 0, 0);
        acc1 = __builtin_amdgcn_mfma_f32_16x16x32_bf16(a1, bfrag, acc1, 0, 0, 0);
        acc2 = __builtin_amdgcn_mfma_f32_16x16x32_bf16(a2, bfrag, acc2, 0, 0, 0);
        acc3 = __builtin_amdgcn_mfma_f32_16x16x32_bf16(a3, bfrag, acc3, 0, 0, 0);
    }

    const float a_s = a[col], a_t = a[OUT_FEAT + col];
    #pragma unroll
    for (int mt = 0; mt < 4; ++mt) {
        const f32x4 av = (mt == 0) ? acc0 : (mt == 1) ? acc1 : (mt == 2) ? acc2 : acc3;
        #pragma unroll
        for (int r = 0; r < 4; ++r) {
            const int lrow = mt * 16 + cgrp * 4 + r;
            const float v = av[r];
            const int grow = r0 + lrow;
            if (grow < N_NODES) WhB[(size_t)grow * OUT_FEAT + col] = f2bf(v);
            float ss = v * a_s;
            float st = v * a_t;
            #pragma unroll
            for (int off = 1; off < 16; off <<= 1) {
                ss += __shfl_xor(ss, off, 64);
                st += __shfl_xor(st, off, 64);
            }
            if (cl == 0) { G.ssp[wid][lrow] = ss; G.stp[wid][lrow] = st; }
        }
    }
    __syncthreads();
    if (tid < 64 && r0 + tid < N_NODES) {
        s_src[r0 + tid] = (G.ssp[0][tid] + G.ssp[1][tid]) + (G.ssp[2][tid] + G.ssp[3][tid]);
        s_tgt[r0 + tid] = (G.stp[0][tid] + G.stp[1][tid]) + (G.stp[2][tid] + G.stp[3][tid]);
    }
}

// Merged sort + aggregation, 1024 threads, FLATTENED register staging:
// subs merged into one index space (c_ofs prefix + 8-way register search) so
// every thread stages ~4 edges (5 static slots); scan; deposit at pfx+rank;
// aggregation with 8-deep gather unroll.  LDS ~41 KB.
__global__ __launch_bounds__(1024) void sort_aggr_kernel(
    const int* __restrict__ cursorA, const int* __restrict__ bucketsA,
    const float* __restrict__ s_src, const float* __restrict__ s_tgt,
    const unsigned short* __restrict__ WhB, float* __restrict__ out)
{
    __shared__ int2 sorted[STAGE_CAP];         // 36864 B (src, w)
    __shared__ float stgt[SB_NODES];
    __shared__ int cnt[SB_NODES];
    __shared__ int pfx[SB_NODES];              // segment begin
    __shared__ unsigned int m_enc[SB_NODES];
    __shared__ int c_ofs[N_SUB + 1];
    __shared__ int wsum[4];
    const int b = blockIdx.x;
    const int tid = threadIdx.x;

    if (tid < SB_NODES) {
        cnt[tid] = 0;
        m_enc[tid] = ENC_NEG_INF;
        const int node = b * SB_NODES + tid;
        stgt[tid] = (node < N_NODES) ? s_tgt[node] : 0.0f;
    }
    if (tid == 0) {
        int o = 0;
        #pragma unroll
        for (int s = 0; s < N_SUB; ++s) {
            c_ofs[s] = o;
            o += cursorA[b * N_SUB + s] - (b * N_SUB + s) * SUBA_CAP;
        }
        c_ofs[N_SUB] = o;
    }
    __syncthreads();
    const int tot = c_ofs[N_SUB];
    int co[N_SUB + 1];
    #pragma unroll
    for (int s = 0; s <= N_SUB; ++s) co[s] = c_ofs[s];

    // pass 1: flattened register staging, 5 static slots (5*1024 >= STAGE_CAP)
    // epk[slot] = src[0:17] | tl[17:25] | rank[25:32); validity in bitmask.
    unsigned int epk[5];
    float ev[5];
    int vmask = 0;
    #pragma unroll
    for (int j = 0; j < 5; ++j) {
        const int k = tid + j * 1024;
        if (k < tot) {
            int s = 0;
            #pragma unroll
            for (int q = 1; q < N_SUB; ++q) s += (k >= co[q]);
            const int pk = bucketsA[(size_t)(b * N_SUB + s) * SUBA_CAP + (k - co[s])];
            const int tl = (pk >> 17) & (SB_NODES - 1);
            float v = s_src[pk & 0x1FFFF] + stgt[tl];
            v = (v >= 0.0f) ? v : LRELU_SLOPE * v;
            const int r = atomicAdd(&cnt[tl], 1);     // rank within node
            atomicMax(&m_enc[tl], enc_f(v));
            epk[j] = ((unsigned int)pk & 0x1FFFFFFu) | ((unsigned int)r << 25);
            ev[j] = v;
            vmask |= 1 << j;
        }
    }
    __syncthreads();

    // exclusive scan of 256 counts via 4-wave shuffle scan (first 256 threads)
    int vv = 0, incl = 0;
    if (tid < SB_NODES) {
        vv = cnt[tid];
        incl = vv;
        #pragma unroll
        for (int off = 1; off < 64; off <<= 1) {
            const int t = __shfl_up(incl, off, 64);
            if ((tid & 63) >= off) incl += t;
        }
        if ((tid & 63) == 63) wsum[tid >> 6] = incl;
    }
    __syncthreads();
    if (tid < SB_NODES) {
        int wpre = 0;
        for (int wv = 0; wv < (tid >> 6); ++wv) wpre += wsum[wv];
        pfx[tid] = wpre + incl - vv;
    }
    __syncthreads();

    // deposit from registers at pfx[tl] + rank (no atomics)
    #pragma unroll
    for (int j = 0; j < 5; ++j) {
        if (vmask & (1 << j)) {
            const unsigned int pk = epk[j];
            const int tl = (int)((pk >> 17) & (SB_NODES - 1));
            const int r = (int)(pk >> 25);
            const float w = __expf(ev[j] - dec_f(m_enc[tl]));
            sorted[pfx[tl] + r] = make_int2((int)(pk & 0x1FFFFu), __float_as_int(w));
        }
    }
    __syncthreads();

    // aggregation: 64 groups of 16 lanes; each group handles 4 nodes; 8-deep ILP
    const int grp = tid >> 4, gl = tid & 15;
    const char* whb = (const char*)WhB;
    const unsigned int foff = (unsigned int)gl << 3;   // 8 B (4 bf16 feats)/lane
    #pragma unroll
    for (int n = 0; n < 4; ++n) {
        const int nl = grp * 4 + n;
        const int node = b * SB_NODES + nl;
        if (node >= N_NODES) continue;
        const int beg = pfx[nl];
        const int end = beg + cnt[nl];
        float a0 = 0.f, a1 = 0.f, a2 = 0.f, a3 = 0.f, sum = 0.f;
        int i = beg;
        for (; i + 8 <= end; i += 8) {
            uint2 g[8]; float w[8];
            #pragma unroll
            for (int e = 0; e < 8; ++e) {
                const int2 pe = sorted[i + e];
                g[e] = *(const uint2*)(whb + (((unsigned int)pe.x << 7) + foff));
                w[e] = __int_as_float(pe.y);
            }
            #pragma unroll
            for (int e = 0; e < 8; ++e) {
                a0 += w[e] * __uint_as_float(g[e].x << 16);
                a1 += w[e] * __uint_as_float(g[e].x & 0xFFFF0000u);
                a2 += w[e] * __uint_as_float(g[e].y << 16);
                a3 += w[e] * __uint_as_float(g[e].y & 0xFFFF0000u);
                sum += w[e];
            }
        }
        for (; i + 4 <= end; i += 4) {
            const int2 p0 = sorted[i],     p1 = sorted[i + 1];
            const int2 p2 = sorted[i + 2], p3 = sorted[i + 3];
            const uint2 g0 = *(const uint2*)(whb + (((unsigned int)p0.x << 7) + foff));
            const uint2 g1 = *(const uint2*)(whb + (((unsigned int)p1.x << 7) + foff));
            const uint2 g2 = *(const uint2*)(whb + (((unsigned int)p2.x << 7) + foff));
            const uint2 g3 = *(const uint2*)(whb + (((unsigned int)p3.x << 7) + foff));
            const float w0 = __int_as_float(p0.y), w1 = __int_as_float(p1.y);
            const float w2 = __int_as_float(p2.y), w3 = __int_as_float(p3.y);
            a0 += w0 * __uint_as_float(g0.x << 16) + w1 * __uint_as_float(g1.x << 16)
                + w2 * __uint_as_float(g2.x << 16) + w3 * __uint_as_float(g3.x << 16);
            a1 += w0 * __uint_as_float(g0.x & 0xFFFF0000u) + w1 * __uint_as_float(g1.x & 0xFFFF0000u)
                + w2 * __uint_as_float(g2.x & 0xFFFF0000u) + w3 * __uint_as_float(g3.x & 0xFFFF0000u);
            a2 += w0 * __uint_as_float(g0.y << 16) + w1 * __uint_as_float(g1.y << 16)
                + w2 * __uint_as_float(g2.y << 16) + w3 * __uint_as_float(g3.y << 16);
            a3 += w0 * __uint_as_float(g0.y & 0xFFFF0000u) + w1 * __uint_as_float(g1.y & 0xFFFF0000u)
                + w2 * __uint_as_float(g2.y & 0xFFFF0000u) + w3 * __uint_as_float(g3.y & 0xFFFF0000u);
            sum += (w0 + w1) + (w2 + w3);
        }
        for (; i < end; ++i) {
            const int2 pk = sorted[i];
            const uint2 g0 = *(const uint2*)(whb + (((unsigned int)pk.x << 7) + foff));
            const float w0 = __int_as_float(pk.y);
            a0 += w0 * __uint_as_float(g0.x << 16);
            a1 += w0 * __uint_as_float(g0.x & 0xFFFF0000u);
            a2 += w0 * __uint_as_float(g0.y << 16);
            a3 += w0 * __uint_as_float(g0.y & 0xFFFF0000u);
            sum += w0;
        }
        const float inv = 1.0f / (sum + EPS_DENOM);
        float4 o;
        o.x = a0 * inv; o.y = a1 * inv; o.z = a2 * inv; o.w = a3 * inv;
        o.x = (o.x > 0.f) ? o.x : expm1f(o.x);
        o.y = (o.y > 0.f) ? o.y : expm1f(o.y);
        o.z = (o.z > 0.f) ? o.z : expm1f(o.z);
        o.w = (o.w > 0.f) ? o.w : expm1f(o.w);
        *(float4*)(out + (size_t)node * OUT_FEAT + (gl << 2)) = o;
    }
}

extern "C" void kernel_launch(void* const* d_in, const int* in_sizes, int n_in,
                              void* d_out, int out_size, void* d_ws, size_t ws_size,
                              hipStream_t stream) {
    const float* x  = (const float*)d_in[0];
    const int*   ei = (const int*)d_in[1];     // int64 in reference -> int32 on device
    const float* W  = (const float*)d_in[2];
    const float* a  = (const float*)d_in[3];
    float* out = (float*)d_out;

    // workspace (~23 MB)
    char* p = (char*)d_ws;
    unsigned short* WhB = (unsigned short*)p; p += (size_t)N_NODES * OUT_FEAT * 2; // 12.8 MB
    unsigned short* WTb = (unsigned short*)p; p += (size_t)OUT_FEAT * IN_FEAT * 2; // 16 KB
    float* s_src    = (float*)p;  p += (size_t)N_NODES * 4;
    float* s_tgt    = (float*)p;  p += (size_t)N_NODES * 4;
    int*   cursorA  = (int*)p;    p += (size_t)NSB * N_SUB * 4;
    p = (char*)(((size_t)p + 15) & ~(size_t)15);
    int*   bucketsA = (int*)p;    p += (size_t)NSB * N_SUB * SUBA_CAP * 4;         // 8.8 MB

    init_prep_kernel<<<32, 256, 0, stream>>>(W, cursorA, WTb);
    gemm_scatter_kernel<<<SCAT_BLOCKS + GEMM_BLOCKS, 256, 0, stream>>>(
        x, WTb, a, ei, cursorA, bucketsA, WhB, s_src, s_tgt);
    sort_aggr_kernel<<<NSB, 1024, 0, stream>>>(cursorA, bucketsA, s_src, s_tgt, WhB, out);
}